// Round 1
// baseline (632.005 us; speedup 1.0000x reference)
//
#include <hip/hip_runtime.h>
#include <hip/hip_bf16.h>
#include <cstdint>
#include <cstddef>

// ---------- types ----------
using u16 = unsigned short;
typedef __attribute__((ext_vector_type(4))) float f32x4;
typedef __attribute__((ext_vector_type(8))) unsigned short u16x8;
typedef __attribute__((ext_vector_type(4))) unsigned short u16x4;
typedef __bf16 bfrag __attribute__((ext_vector_type(8)));   // 8 bf16 = 4 VGPR MFMA operand

constexpr int Hn = 8, Cn = 1024, Dn = 128, Fn = 512, Bn = 16;
constexpr int M1 = Bn * Cn;  // 16384 rows of x / att_out

// workspace layout (bytes)
constexpr size_t OFF_XB  = 0;                                  // x bf16 [16384][512]
constexpr size_t SZ_XB   = (size_t)M1 * Fn * 2;                // 16 MiB
constexpr size_t OFF_WT  = OFF_XB + SZ_XB;                     // Wt bf16 [3][1024][512] (q,k,v)
constexpr size_t SZ_WT   = 3ull * 1024 * 512 * 2;              // 3 MiB
constexpr size_t OFF_W0T = OFF_WT + SZ_WT;                     // Ww0^T bf16 [128][1024]
constexpr size_t SZ_W0T  = 128ull * 1024 * 2;
constexpr size_t OFF_Q   = OFF_W0T + SZ_W0T;                   // q perm [16][8][1024][128] bf16
constexpr size_t SZ_P    = (size_t)Bn * Hn * Cn * Dn * 2;      // 32 MiB each
constexpr size_t OFF_K   = OFF_Q + SZ_P;
constexpr size_t OFF_V   = OFF_K + SZ_P;
constexpr size_t OFF_ATT = OFF_V + SZ_P;                       // vals2 bf16 [16384][1024]

// ---------- helpers ----------
__device__ __forceinline__ float bf2f(u16 u) {
  unsigned int x = ((unsigned int)u) << 16;
  return __builtin_bit_cast(float, x);
}
__device__ __forceinline__ u16 f2bf(float f) {
  unsigned int u = __builtin_bit_cast(unsigned int, f);
  u += 0x7fffu + ((u >> 16) & 1u);   // RNE
  return (u16)(u >> 16);
}
__device__ __forceinline__ f32x4 mfma16(bfrag a, bfrag b, f32x4 c) {
  return __builtin_amdgcn_mfma_f32_16x16x32_bf16(a, b, c, 0, 0, 0);
}
// async 16B global->LDS; lds base must be wave-uniform (lane*16 auto-offset)
__device__ __forceinline__ void gload16(const void* g, void* lds) {
  __builtin_amdgcn_global_load_lds(
      (const __attribute__((address_space(1))) unsigned int*)g,
      (__attribute__((address_space(3))) unsigned int*)lds, 16, 0, 0);
}

// ---------- prep kernels ----------
__global__ void cvt_bf16(const float* __restrict__ in, u16* __restrict__ out, int n) {
  int idx = (blockIdx.x * blockDim.x + threadIdx.x) * 4;
  if (idx < n) {
    float4 v = *(const float4*)(in + idx);
    u16x4 o;
    o.x = f2bf(v.x); o.y = f2bf(v.y); o.z = f2bf(v.z); o.w = f2bf(v.w);
    *(u16x4*)(out + idx) = o;
  }
}

// in [R][Cc] f32 -> out [Cc][R] bf16 ; block (32,8), grid (Cc/32, R/32)
__global__ void transpose_cvt(const float* __restrict__ in, u16* __restrict__ out,
                              int R, int Cc) {
  __shared__ float tile[32][33];
  int c0 = blockIdx.x * 32, r0 = blockIdx.y * 32;
  int tx = threadIdx.x, ty = threadIdx.y;
#pragma unroll
  for (int i = 0; i < 4; ++i)
    tile[ty + i * 8][tx] = in[(size_t)(r0 + ty + i * 8) * Cc + c0 + tx];
  __syncthreads();
#pragma unroll
  for (int i = 0; i < 4; ++i)
    out[(size_t)(c0 + ty + i * 8) * R + r0 + tx] = f2bf(tile[tx][ty + i * 8]);
}

// ---------- QKV projection GEMM ----------
// A = xb [16384][512] bf16, B^T = wt[p] [1024][512] bf16. Tile 128x128, BK=64.
// Epilogue writes bias-added bf16 into the "mixed reshape" perm layout [B][H][C][D].
__global__ void qkv_gemm(const u16* __restrict__ xb, const u16* __restrict__ wt,
                         const float* __restrict__ bq, const float* __restrict__ bk,
                         const float* __restrict__ bv,
                         u16* __restrict__ qout, u16* __restrict__ kout,
                         u16* __restrict__ vout) {
  __shared__ u16 As[128 * 64];
  __shared__ u16 Bs[128 * 64];
  const int m0 = blockIdx.x * 128;
  const int n0 = blockIdx.y * 128;
  const int p  = blockIdx.z;
  const u16* wp = wt + (size_t)p * 1024 * 512;
  const float* bias = (p == 0) ? bq : (p == 1) ? bk : bv;
  u16* outp = (p == 0) ? qout : (p == 1) ? kout : vout;

  const int tid = threadIdx.x, l = tid & 63, w = tid >> 6;
  const int lr = l & 15, lg = l >> 4;
  const int wr = w >> 1, wc = w & 1;

  f32x4 acc[4][4] = {};

  for (int kt = 0; kt < Fn; kt += 64) {
    // stage A, B: 1024 chunks each (row = ch>>3, 8 chunks of 16B per 128B row),
    // source col-chunk XOR-preswizzled so swizzled LDS reads are conflict-light
#pragma unroll
    for (int i = 0; i < 4; ++i) {
      int chb = (i * 4 + w) * 64;
      int ch = chb + l;
      int row = ch >> 3, scc = (ch & 7) ^ (row & 7);
      gload16(xb + (size_t)(m0 + row) * Fn + kt + scc * 8, &As[chb * 8]);
    }
#pragma unroll
    for (int i = 0; i < 4; ++i) {
      int chb = (i * 4 + w) * 64;
      int ch = chb + l;
      int row = ch >> 3, scc = (ch & 7) ^ (row & 7);
      gload16(wp + (size_t)(n0 + row) * Fn + kt + scc * 8, &Bs[chb * 8]);
    }
    __syncthreads();
#pragma unroll
    for (int kk = 0; kk < 2; ++kk) {
      bfrag af[4], bf_[4];
#pragma unroll
      for (int fm = 0; fm < 4; ++fm) {
        int row = wr * 64 + fm * 16 + lr;
        int off = (kk * 4 + lg) ^ (row & 7);
        af[fm] = *(const bfrag*)&As[row * 64 + off * 8];
      }
#pragma unroll
      for (int fn = 0; fn < 4; ++fn) {
        int row = wc * 64 + fn * 16 + lr;
        int off = (kk * 4 + lg) ^ (row & 7);
        bf_[fn] = *(const bfrag*)&Bs[row * 64 + off * 8];
      }
#pragma unroll
      for (int fm = 0; fm < 4; ++fm)
#pragma unroll
        for (int fn = 0; fn < 4; ++fn)
          acc[fm][fn] = mfma16(af[fm], bf_[fn], acc[fm][fn]);
    }
    __syncthreads();
  }

  // epilogue: perm write  (h'=c>>7, c'=(c&127)*8+(j>>7), d=j&127)
#pragma unroll
  for (int fm = 0; fm < 4; ++fm) {
#pragma unroll
    for (int r = 0; r < 4; ++r) {
      int m = m0 + wr * 64 + fm * 16 + lg * 4 + r;
      int b = m >> 10, c = m & 1023;
      int gh = c >> 7;
#pragma unroll
      for (int fn = 0; fn < 4; ++fn) {
        int j = n0 + wc * 64 + fn * 16 + lr;
        float v = acc[fm][fn][r] + bias[j];
        int ii = ((c & 127) << 3) | (j >> 7);
        int d = j & 127;
        size_t idx = (((size_t)(b * 8 + gh) * 1024 + ii) << 7) | d;
        outp[idx] = f2bf(v);
      }
    }
  }
}

// ---------- fused flash attention (per (b,h) head, O = softmax(QK^T/sqrt(D))@V - V) ----------
// grid (8 qtiles, 128 bh), 256 threads = 4 waves, wave owns 32 q-rows.
__global__ void attn_kernel(const u16* __restrict__ qp_all, const u16* __restrict__ kp_all,
                            const u16* __restrict__ vp_all, u16* __restrict__ attout) {
  __shared__ u16 Ks[64 * 128];      // K tile, XOR-swizzled chunks, linear (global_load_lds)
  __shared__ u16 Vt[128 * 72];      // V^T tile [d][kv], pitch 72 (rows 144B, 16B-aligned)
  __shared__ u16 Ps[4][32 * 72];    // per-wave P tile [32][64], pitch 72

  const int qt = blockIdx.x;
  const int bh = blockIdx.y;
  const int tid = threadIdx.x, l = tid & 63, w = tid >> 6;
  const int lr = l & 15, lg = l >> 4;

  const u16* qp = qp_all + (size_t)bh * (Cn * Dn);
  const u16* kp = kp_all + (size_t)bh * (Cn * Dn);
  const u16* vp = vp_all + (size_t)bh * (Cn * Dn);
  const int qr0 = qt * 128 + w * 32;

  // Q fragments in registers for the whole kernel
  bfrag aq[2][4];
#pragma unroll
  for (int fm = 0; fm < 2; ++fm)
#pragma unroll
    for (int kk = 0; kk < 4; ++kk)
      aq[fm][kk] = *(const bfrag*)(qp + (size_t)(qr0 + fm * 16 + lr) * Dn + kk * 32 + lg * 8);

  f32x4 o[2][8] = {};
  float mst[2][4], lst[2][4];
#pragma unroll
  for (int a = 0; a < 2; ++a)
#pragma unroll
    for (int r = 0; r < 4; ++r) { mst[a][r] = -1e30f; lst[a][r] = 0.f; }

  const float scale = 0.08838834764831845f;  // 1/sqrt(128)

  for (int t = 0; t < 16; ++t) {
    // stage K [64][128]: 1024 chunks, 16 chunks/row, source pre-swizzled
#pragma unroll
    for (int i = 0; i < 4; ++i) {
      int chb = (i * 4 + w) * 64;
      int ch = chb + l;
      int row = ch >> 4, scc = (ch & 15) ^ (row & 7);
      gload16(kp + (size_t)(t * 64 + row) * Dn + scc * 8, &Ks[chb * 8]);
    }
    // stage V^T via regs: lane = kv row, wave = 32-col d segment
    {
      const u16* vrow = vp + (size_t)(t * 64 + l) * Dn + w * 32;
#pragma unroll
      for (int i = 0; i < 4; ++i) {
        u16x8 vv = *(const u16x8*)(vrow + i * 8);
#pragma unroll
        for (int j2 = 0; j2 < 8; ++j2)
          Vt[(w * 32 + i * 8 + j2) * 72 + l] = vv[j2];
      }
    }
    __syncthreads();

    // S = Q K^T  (per wave: [32 rows][64 cols])
    f32x4 s[2][4] = {};
#pragma unroll
    for (int kk = 0; kk < 4; ++kk) {
      bfrag bk_[4];
#pragma unroll
      for (int fn = 0; fn < 4; ++fn) {
        int row = fn * 16 + lr;
        int off = (kk * 4 + lg) ^ (row & 7);
        bk_[fn] = *(const bfrag*)&Ks[row * 128 + off * 8];
      }
#pragma unroll
      for (int fm = 0; fm < 2; ++fm)
#pragma unroll
        for (int fn = 0; fn < 4; ++fn)
          s[fm][fn] = mfma16(aq[fm][kk], bk_[fn], s[fm][fn]);
    }
#pragma unroll
    for (int fm = 0; fm < 2; ++fm)
#pragma unroll
      for (int fn = 0; fn < 4; ++fn)
#pragma unroll
        for (int r = 0; r < 4; ++r) s[fm][fn][r] *= scale;

    // online softmax (row = fm*16 + lg*4 + r, spread over 16 lanes by col)
#pragma unroll
    for (int fm = 0; fm < 2; ++fm) {
#pragma unroll
      for (int r = 0; r < 4; ++r) {
        float mx = fmaxf(fmaxf(s[fm][0][r], s[fm][1][r]), fmaxf(s[fm][2][r], s[fm][3][r]));
#pragma unroll
        for (int mk = 1; mk < 16; mk <<= 1) mx = fmaxf(mx, __shfl_xor(mx, mk, 64));
        float mold = mst[fm][r];
        float mnew = fmaxf(mold, mx);
        float alpha = __expf(mold - mnew);
        mst[fm][r] = mnew;
        float rs = 0.f;
#pragma unroll
        for (int fn = 0; fn < 4; ++fn) {
          float pv = __expf(s[fm][fn][r] - mnew);
          s[fm][fn][r] = pv;
          rs += pv;
        }
#pragma unroll
        for (int mk = 1; mk < 16; mk <<= 1) rs += __shfl_xor(rs, mk, 64);
        lst[fm][r] = lst[fm][r] * alpha + rs;
#pragma unroll
        for (int fn2 = 0; fn2 < 8; ++fn2) o[fm][fn2][r] *= alpha;
      }
    }

    // P -> per-wave LDS (bf16), then PV MFMA
#pragma unroll
    for (int fm = 0; fm < 2; ++fm)
#pragma unroll
      for (int fn = 0; fn < 4; ++fn)
#pragma unroll
        for (int r = 0; r < 4; ++r)
          Ps[w][(fm * 16 + lg * 4 + r) * 72 + fn * 16 + lr] = f2bf(s[fm][fn][r]);

#pragma unroll
    for (int kk = 0; kk < 2; ++kk) {
      bfrag ap[2];
#pragma unroll
      for (int fm = 0; fm < 2; ++fm)
        ap[fm] = *(const bfrag*)&Ps[w][(fm * 16 + lr) * 72 + kk * 32 + lg * 8];
#pragma unroll
      for (int fn2 = 0; fn2 < 8; ++fn2) {
        bfrag bv_ = *(const bfrag*)&Vt[(fn2 * 16 + lr) * 72 + kk * 32 + lg * 8];
#pragma unroll
        for (int fm = 0; fm < 2; ++fm)
          o[fm][fn2] = mfma16(ap[fm], bv_, o[fm][fn2]);
      }
    }
    __syncthreads();
  }

  // epilogue: O/l - V[row]; write vals2[b, c', h*128+d] as bf16
  const int b = bh >> 3, h = bh & 7;
#pragma unroll
  for (int fm = 0; fm < 2; ++fm) {
#pragma unroll
    for (int r = 0; r < 4; ++r) {
      int c1 = qr0 + fm * 16 + lg * 4 + r;
      float inv = 1.f / lst[fm][r];
      const u16* vrow = vp + (size_t)c1 * Dn;
      u16* orow = attout + ((size_t)(b * 1024 + c1) * 8 + h) * 128;
#pragma unroll
      for (int fn2 = 0; fn2 < 8; ++fn2) {
        int d = fn2 * 16 + lr;
        float val = o[fm][fn2][r] * inv - bf2f(vrow[d]);
        orow[d] = f2bf(val);
      }
    }
  }
}

// ---------- output GEMM: [16384][1024] @ [1024][128] + bias -> f32 ----------
__global__ void out_gemm(const u16* __restrict__ A, const u16* __restrict__ Bt,
                         const float* __restrict__ bias, float* __restrict__ out) {
  __shared__ u16 As[64 * 64];
  __shared__ u16 Bs[128 * 64];
  const int m0 = blockIdx.x * 64;
  const int tid = threadIdx.x, l = tid & 63, w = tid >> 6;
  const int lr = l & 15, lg = l >> 4;
  const int wr = w >> 1, wc = w & 1;
  f32x4 acc[2][4] = {};

  for (int kt = 0; kt < 1024; kt += 64) {
#pragma unroll
    for (int i = 0; i < 2; ++i) {
      int chb = (i * 4 + w) * 64;
      int ch = chb + l;
      int row = ch >> 3, scc = (ch & 7) ^ (row & 7);
      gload16(A + (size_t)(m0 + row) * 1024 + kt + scc * 8, &As[chb * 8]);
    }
#pragma unroll
    for (int i = 0; i < 4; ++i) {
      int chb = (i * 4 + w) * 64;
      int ch = chb + l;
      int row = ch >> 3, scc = (ch & 7) ^ (row & 7);
      gload16(Bt + (size_t)row * 1024 + kt + scc * 8, &Bs[chb * 8]);
    }
    __syncthreads();
#pragma unroll
    for (int kk = 0; kk < 2; ++kk) {
      bfrag af[2], bf_[4];
#pragma unroll
      for (int fm = 0; fm < 2; ++fm) {
        int row = wr * 32 + fm * 16 + lr;
        int off = (kk * 4 + lg) ^ (row & 7);
        af[fm] = *(const bfrag*)&As[row * 64 + off * 8];
      }
#pragma unroll
      for (int fn = 0; fn < 4; ++fn) {
        int row = wc * 64 + fn * 16 + lr;
        int off = (kk * 4 + lg) ^ (row & 7);
        bf_[fn] = *(const bfrag*)&Bs[row * 64 + off * 8];
      }
#pragma unroll
      for (int fm = 0; fm < 2; ++fm)
#pragma unroll
        for (int fn = 0; fn < 4; ++fn)
          acc[fm][fn] = mfma16(af[fm], bf_[fn], acc[fm][fn]);
    }
    __syncthreads();
  }
#pragma unroll
  for (int fm = 0; fm < 2; ++fm)
#pragma unroll
    for (int r = 0; r < 4; ++r) {
      int m = m0 + wr * 32 + fm * 16 + lg * 4 + r;
#pragma unroll
      for (int fn = 0; fn < 4; ++fn) {
        int j = wc * 64 + fn * 16 + lr;
        out[(size_t)m * 128 + j] = acc[fm][fn][r] + bias[j];
      }
    }
}

// ---------- launch ----------
extern "C" void kernel_launch(void* const* d_in, const int* in_sizes, int n_in,
                              void* d_out, int out_size, void* d_ws, size_t ws_size,
                              hipStream_t stream) {
  const float* x   = (const float*)d_in[0];
  const float* Wk  = (const float*)d_in[1];
  const float* bk_ = (const float*)d_in[2];
  const float* Wq  = (const float*)d_in[3];
  const float* bq_ = (const float*)d_in[4];
  const float* Wv  = (const float*)d_in[5];
  const float* bv_ = (const float*)d_in[6];
  const float* Ww0 = (const float*)d_in[7];
  const float* bw0 = (const float*)d_in[8];
  float* out = (float*)d_out;

  char* ws = (char*)d_ws;
  u16* xb   = (u16*)(ws + OFF_XB);
  u16* wt   = (u16*)(ws + OFF_WT);
  u16* w0t  = (u16*)(ws + OFF_W0T);
  u16* qpm  = (u16*)(ws + OFF_Q);
  u16* kpm  = (u16*)(ws + OFF_K);
  u16* vpm  = (u16*)(ws + OFF_V);
  u16* attb = (u16*)(ws + OFF_ATT);

  // prep: cast x, transpose+cast weights
  cvt_bf16<<<(M1 * Fn / 4 + 255) / 256, 256, 0, stream>>>(x, xb, M1 * Fn);
  dim3 tb(32, 8);
  transpose_cvt<<<dim3(32, 16), tb, 0, stream>>>(Wq, wt + 0 * 1024 * 512, 512, 1024);
  transpose_cvt<<<dim3(32, 16), tb, 0, stream>>>(Wk, wt + 1 * 1024 * 512, 512, 1024);
  transpose_cvt<<<dim3(32, 16), tb, 0, stream>>>(Wv, wt + 2 * 1024 * 512, 512, 1024);
  transpose_cvt<<<dim3(4, 32),  tb, 0, stream>>>(Ww0, w0t, 1024, 128);

  // projections -> permuted q/k/v (bf16)
  qkv_gemm<<<dim3(128, 8, 3), 256, 0, stream>>>(xb, wt, bq_, bk_, bv_, qpm, kpm, vpm);

  // fused attention (softmax - I folded as O = P@V - V)
  attn_kernel<<<dim3(8, 128), 256, 0, stream>>>(qpm, kpm, vpm, attb);

  // output projection (f32 out + bias)
  out_gemm<<<256, 256, 0, stream>>>(attb, w0t, bw0, out);
}